// Round 13
// baseline (128.353 us; speedup 1.0000x reference)
//
#include <hip/hip_runtime.h>
#include <hip/hip_bf16.h>

// ConvTranspose4d: B=2, CIN=32, COUT=32, S=16^4, K=3^4, pad=0, stride=1
// y[b,co,o] = bias[co] + sum_{ci,k} x[b,ci,o-k] w[ci,co,k],  out spatial 18^4.
//
// R10 (bf16 MFMA + prepack): 112.7us total, both kernels <46us each. Staging was
// synchronous per (k0,k1): barrier -> global load -> LDS write -> barrier (latency
// exposed). R11: T14 async-STAGE split — prefetch next plane/slab into REGISTERS
// during current MFMA phase; after read-barrier only regs->LDS + barrier.
// w_t now prepacked in the exact LDS slab image. MFMA order a0*3 then a1*3.

#define B_    2
#define CIN_  32
#define SD    16
#define OD    18
#define NTAP  81
#define THREADS 256

typedef unsigned short u16;
typedef __attribute__((ext_vector_type(8))) short short8v;
typedef __attribute__((ext_vector_type(8))) unsigned short u16x8;
typedef __attribute__((ext_vector_type(16))) float f32x16;

__device__ inline u16 f2bf(float f) {
    unsigned u = __float_as_uint(f);
    u = (u + 0x7FFFu + ((u >> 16) & 1u)) >> 16;   // RNE
    return (u16)u;
}

__device__ inline void decode_o01(int r, int& o0, int& o1) {
    if (r < 196) { o0 = 2 + r / 14; o1 = 2 + r % 14; }
    else if (r < 252) { int q = r - 196;
        if (q < 28) { o0 = 2 + (q >> 1); o1 = (q & 1) ? 16 : 1; }
        else { q -= 28; o1 = 2 + (q >> 1); o0 = (q & 1) ? 16 : 1; } }
    else if (r < 256) { int q = r - 252; o0 = (q & 1) ? 16 : 1; o1 = (q >> 1) ? 16 : 1; }
    else if (r < 312) { int q = r - 256;
        if (q < 28) { o0 = 2 + (q >> 1); o1 = (q & 1) ? 17 : 0; }
        else { q -= 28; o1 = 2 + (q >> 1); o0 = (q & 1) ? 17 : 0; } }
    else if (r < 320) { int q = r - 312;
        if (q < 4) { o0 = (q & 1) ? 16 : 1; o1 = (q >> 1) ? 17 : 0; }
        else { q -= 4; o0 = (q & 1) ? 17 : 0; o1 = (q >> 1) ? 16 : 1; } }
    else { int q = r - 320; o0 = (q & 1) ? 17 : 0; o1 = (q >> 1) ? 17 : 0; }
}

// ---- prepack: x_t [b*256+plane][cg:4][pos:256][8ci] bf16 ; w_t = 9 LDS slab images
//      slab s=(k0*3+k1): [tap:9][g:4][co:32][8ci] bf16 (18432 B each)
__global__ __launch_bounds__(THREADS)
void prepack_kernel(const float* __restrict__ x, const float* __restrict__ w,
                    u16* __restrict__ xt, u16* __restrict__ wt) {
    const int bid = blockIdx.x, t = threadIdx.x;
    if (bid < 512) {
        const int b = bid >> 8, plane = bid & 255;
        const float* xp = x + (size_t)b * 32 * 65536 + plane * 256 + t;
#pragma unroll
        for (int cg = 0; cg < 4; ++cg) {
            u16x8 v;
#pragma unroll
            for (int j = 0; j < 8; ++j)
                v[j] = f2bf(xp[(size_t)(cg * 8 + j) * 65536]);
            *(u16x8*)(xt + ((size_t)(bid * 4 + cg) * 256 + t) * 8) = v;
        }
    } else {
        const int s = bid - 512;                   // slab 0..8 = k0*3+k1
#pragma unroll
        for (int q = 0; q < 5; ++q) {
            const int idx = t + q * 256;
            if (idx < 1152) {
                const int tt = idx >> 7, r = idx & 127, g = r >> 5, co = r & 31;
                u16x8 v;
#pragma unroll
                for (int e = 0; e < 8; ++e)
                    v[e] = f2bf(w[((size_t)(g * 8 + e) * 32 + co) * NTAP + s * 9 + tt]);
                *(u16x8*)(wt + (size_t)s * 9216 + (size_t)idx * 8) = v;
            }
        }
    }
}

// ---- main MFMA kernel ----
// LDS: x_plane [cg:4][20x20 pos'][8ci] = 25600 B (zero borders, written once)
//      w_slab at +25600: 18432 B ; epilogue overlay [324][33]f32 = 42768 B
__global__ __launch_bounds__(THREADS)
void convt4d_mfma(const u16* __restrict__ xt, const u16* __restrict__ wt,
                  const float* __restrict__ bias, float* __restrict__ y) {
    const int bid = blockIdx.x;
    const int b = bid & 1;
    int o0, o1; decode_o01(bid >> 1, o0, o1);
    const int t = threadIdx.x, l = t & 63, wv = t >> 6;
    const int hi = l >> 5, ln = l & 31;

    const int k0lo = max(0, o0 - (SD - 1)), k0hi = min(2, o0);
    const int k1lo = max(0, o1 - (SD - 1)), k1hi = min(2, o1);

    __shared__ __align__(16) char smem[44032];

    // zero x region once (borders stay zero; interior rewritten per plane)
    for (int u = t; u < 1600; u += THREADS)
        *(float4*)(smem + u * 16) = make_float4(0.f, 0.f, 0.f, 0.f);

    int tiles[3] = { wv, wv + 4, (wv + 8) % 11 };
    int lpos[3];
#pragma unroll
    for (int mi = 0; mi < 3; ++mi) {
        int p = 32 * tiles[mi] + ln; p = p > 323 ? 323 : p;
        const int o2p = p / 18, o3p = p - o2p * 18;
        lpos[mi] = (o2p + 2) * 20 + o3p + 2;
    }

    f32x16 acc[3];
    { const float bb = bias[ln];
#pragma unroll
      for (int mi = 0; mi < 3; ++mi)
#pragma unroll
        for (int r = 0; r < 16; ++r) acc[mi][r] = bb;
    }

    // prefetch registers
    u16x8 xv[4], wvr[5];

#define PREF(K0, K1) do {                                                      \
        const int plane_ = (o0 - (K0)) * 16 + (o1 - (K1));                     \
        const u16* xs_ = xt + (size_t)(b * 256 + plane_) * 8192;               \
        _Pragma("unroll")                                                      \
        for (int q = 0; q < 4; ++q) xv[q] = *(const u16x8*)(xs_ + (t + q*256)*8); \
        const u16* ws_ = wt + (size_t)((K0) * 3 + (K1)) * 9216;                \
        _Pragma("unroll")                                                      \
        for (int q = 0; q < 5; ++q) { const int idx_ = t + q*256;              \
            if (idx_ < 1152) wvr[q] = *(const u16x8*)(ws_ + (size_t)idx_*8); } \
    } while (0)

#define WRITE() do {                                                           \
        _Pragma("unroll")                                                      \
        for (int q = 0; q < 4; ++q)                                            \
            *(u16x8*)(smem + (q*400 + ((t>>4)+2)*20 + (t&15) + 2) * 16) = xv[q]; \
        _Pragma("unroll")                                                      \
        for (int q = 0; q < 5; ++q) { const int idx_ = t + q*256;              \
            if (idx_ < 1152) *(u16x8*)(smem + 25600 + idx_*16) = wvr[q]; }     \
    } while (0)

    PREF(k0lo, k1lo);
    WRITE();
    __syncthreads();

    int k0 = k0lo, k1 = k1lo;
    while (true) {
        int nk0 = k0, nk1 = k1 + 1;
        if (nk1 > k1hi) { nk0 = k0 + 1; nk1 = k1lo; }
        const bool has_next = (nk0 <= k0hi);
        if (has_next) PREF(nk0, nk1);     // global->regs, completes under compute

        // ---- compute current (k0,k1) from LDS ----
#pragma unroll
        for (int tt = 0; tt < 9; ++tt) {
            const int sh = (tt / 3) * 20 + (tt % 3);
            const int wb = 25600 + tt * 2048 + hi * 512 + ln * 16;
            short8v b0 = *(const short8v*)(smem + wb);
            short8v b1 = *(const short8v*)(smem + wb + 1024);
            short8v A0[3], A1[3];
#pragma unroll
            for (int mi = 0; mi < 3; ++mi) {
                const int ab = (hi * 400 + lpos[mi] - sh) * 16;
                A0[mi] = *(const short8v*)(smem + ab);
                A1[mi] = *(const short8v*)(smem + ab + 12800);
            }
#pragma unroll
            for (int mi = 0; mi < 3; ++mi)
                acc[mi] = __builtin_amdgcn_mfma_f32_32x32x16_bf16(A0[mi], b0, acc[mi], 0, 0, 0);
#pragma unroll
            for (int mi = 0; mi < 3; ++mi)
                acc[mi] = __builtin_amdgcn_mfma_f32_32x32x16_bf16(A1[mi], b1, acc[mi], 0, 0, 0);
        }
        __syncthreads();                  // all reads of current LDS done
        if (!has_next) break;
        WRITE();                          // regs -> LDS (next)
        __syncthreads();
        k0 = nk0; k1 = nk1;
    }

    // ---- epilogue: D -> LDS transpose -> coalesced stores ----
#pragma unroll
    for (int mi = 0; mi < 3; ++mi) {
        const int pb = 32 * tiles[mi] + 4 * hi;
#pragma unroll
        for (int r = 0; r < 16; ++r) {
            const int p = pb + (r & 3) + 8 * (r >> 2);
            if (p < 324) *(float*)(smem + (p * 33 + ln) * 4) = acc[mi][r];
        }
    }
    __syncthreads();
    {
        const size_t ybase = (size_t)b * 32 * 104976 + (size_t)(o0 * 18 + o1) * 324;
        for (int co = 0; co < 32; ++co) {
            const float v0 = *(const float*)(smem + (t * 33 + co) * 4);
            y[ybase + (size_t)co * 104976 + t] = v0;
            if (t < 324 - 256) {
                const float v1 = *(const float*)(smem + ((t + 256) * 33 + co) * 4);
                y[ybase + (size_t)co * 104976 + t + 256] = v1;
            }
        }
    }
#undef PREF
#undef WRITE
}

// ---- fallback (r9 fp32 kernel) ----
__global__ __launch_bounds__(576, 5)
void convt4d_fp32(const float* __restrict__ x, const float* __restrict__ w,
                  const float* __restrict__ bias, float* __restrict__ y) {
    const int bid = blockIdx.x;
    const int b = bid & 1;
    int o0, o1; decode_o01(bid >> 1, o0, o1);
    const int t = threadIdx.x;
    const int co = t & 15, rr_ = t >> 4, h = rr_ & 1, o2 = rr_ >> 1, i3b = h * 8;
    const int k0lo = max(0, o0 - (SD - 1)), k0hi = min(2, o0);
    const int k1lo = max(0, o1 - (SD - 1)), k1hi = min(2, o1);
    const int n0 = k0hi - k0lo + 1, n1 = k1hi - k1lo + 1;
    __shared__ float4 xs4[2][3][3][64];
    __shared__ float wsl[2 * 32 * NTAP];
    float a0[10], a1[10];
#pragma unroll
    for (int j = 0; j < 10; ++j) { a0[j] = 0.f; a1[j] = 0.f; }
    for (int cc = 0; cc < CIN_; cc += 2) {
        const int total4 = 2 * n0 * n1 * 64;
        for (int idx = t; idx < total4; idx += 576) {
            const int rw = idx >> 6, e = idx & 63;
            const int ci = rw / (n0 * n1), r2 = rw - ci * (n0 * n1);
            const int s0 = r2 / n1, s1 = r2 - s0 * n1;
            const int i0 = o0 - (k0lo + s0), i1 = o1 - (k1lo + s1);
            xs4[ci][s0][s1][e] = ((const float4*)(x +
                ((((size_t)b * CIN_ + (cc + ci)) * SD + i0) * SD + i1) * 256))[e];
        }
        const float4* src = (const float4*)(w + (size_t)cc * 32 * NTAP);
        for (int idx = t; idx < 2 * 32 * NTAP / 4; idx += 576)
            ((float4*)wsl)[idx] = src[idx];
        __syncthreads();
        for (int ci = 0; ci < 2; ++ci)
        for (int s0 = 0; s0 < n0; ++s0)
        for (int s1 = 0; s1 < n1; ++s1) {
            const int k0 = k0lo + s0, k1 = k1lo + s1;
            const float* wp0 = &wsl[(ci * 32 + co) * NTAP + (k0 * 3 + k1) * 9];
            const float* wp1 = wp0 + 16 * NTAP;
            float wv0[9], wv1[9];
#pragma unroll
            for (int q = 0; q < 9; ++q) { wv0[q] = wp0[q]; wv1[q] = wp1[q]; }
            const float* base = (const float*)xs4[ci][s0][s1];
#pragma unroll
            for (int k2 = 0; k2 < 3; ++k2) {
                const int i2 = o2 - k2;
                if ((unsigned)i2 < (unsigned)SD) {
                    const float* xr = base + i2 * SD + i3b;
                    const float4 xa = ((const float4*)xr)[0];
                    const float4 xb = ((const float4*)xr)[1];
                    const float xv[8] = {xa.x, xa.y, xa.z, xa.w, xb.x, xb.y, xb.z, xb.w};
#pragma unroll
                    for (int k3 = 0; k3 < 3; ++k3) {
                        const float c0 = wv0[k2 * 3 + k3], c1 = wv1[k2 * 3 + k3];
#pragma unroll
                        for (int m = 0; m < 8; ++m) {
                            a0[m + k3] += c0 * xv[m]; a1[m + k3] += c1 * xv[m];
                        }
                    }
                }
            }
        }
        __syncthreads();
    }
    float* bnd = (float*)xs4;
    const int slot = (o2 * 16 + co) * 4;
    if (h == 0) { bnd[slot] = a0[8]; bnd[slot + 1] = a0[9]; bnd[slot + 2] = a1[8]; bnd[slot + 3] = a1[9]; }
    __syncthreads();
    const float bb0 = bias[co], bb1 = bias[co + 16];
    float* y0 = y + (((((size_t)b * 32 + co) * OD + o0) * OD + o1) * OD + o2) * OD;
    float* y1 = y0 + (size_t)16 * OD * OD * OD * OD;
    if (h == 0) {
#pragma unroll
        for (int j = 0; j < 4; ++j) {
            ((float2*)y0)[j] = make_float2(a0[2 * j] + bb0, a0[2 * j + 1] + bb0);
            ((float2*)y1)[j] = make_float2(a1[2 * j] + bb1, a1[2 * j + 1] + bb1);
        }
    } else {
        a0[0] += bnd[slot]; a0[1] += bnd[slot + 1]; a1[0] += bnd[slot + 2]; a1[1] += bnd[slot + 3];
#pragma unroll
        for (int j = 0; j < 5; ++j) {
            ((float2*)(y0 + 8))[j] = make_float2(a0[2 * j] + bb0, a0[2 * j + 1] + bb0);
            ((float2*)(y1 + 8))[j] = make_float2(a1[2 * j] + bb1, a1[2 * j + 1] + bb1);
        }
    }
}

extern "C" void kernel_launch(void* const* d_in, const int* in_sizes, int n_in,
                              void* d_out, int out_size, void* d_ws, size_t ws_size,
                              hipStream_t stream) {
    const float* x    = (const float*)d_in[0];
    const float* w    = (const float*)d_in[1];
    const float* bias = (const float*)d_in[2];
    float* y = (float*)d_out;

    const size_t WT_BYTES = 262144;                       // 9 slabs (166KB) + pad
    const size_t XT_BYTES = (size_t)512 * 1024 * 16;      // 8.39 MB
    if (ws_size >= WT_BYTES + XT_BYTES) {
        u16* wt = (u16*)d_ws;
        u16* xt = (u16*)((char*)d_ws + WT_BYTES);
        prepack_kernel<<<521, THREADS, 0, stream>>>(x, w, xt, wt);
        convt4d_mfma<<<B_ * OD * OD, THREADS, 0, stream>>>(xt, wt, bias, y);
    } else {
        convt4d_fp32<<<B_ * OD * OD, 576, 0, stream>>>(x, w, bias, y);
    }
}